// Round 1
// baseline (997.614 us; speedup 1.0000x reference)
//
#include <hip/hip_runtime.h>
#include <hip/hip_bf16.h>

// GCN link-prediction: 2x GCNConv (add self-loops, symmetric norm) + dot decoder.
// N=50000 nodes, F_in=50, H=50, D=64, E_train=1.6M, Ep=En=200k.
//
// Pipeline per call (ws is re-poisoned 0xAA every launch, so zero what we need):
//   memset(deg, out1, out2)
//   deg <- scatter ones over train targets;  dinv = rsqrt(deg+1)   (+1 = self loop)
//   h1  = x @ W1                       (W in LDS, 1 thread/elem)
//   out1 <- atomic scatter h1[row]*dinv[row]*dinv[col] over col    (1 wave/edge)
//   out1 = relu(out1 + h1*dinv^2 + b1)                             (self loop + bias fused)
//   hz  = out1 @ W2
//   out2 <- atomic scatter, epilogue (no relu) -> z
//   logits[e] = dot64(z[a], z[b])                                  (1 wave/edge, shuffle reduce)

__global__ __launch_bounds__(256) void deg_kernel(const int* __restrict__ col, int E,
                                                  float* __restrict__ deg) {
    int i = blockIdx.x * blockDim.x + threadIdx.x;
    if (i < E) atomicAdd(&deg[col[i]], 1.0f);
}

__global__ __launch_bounds__(256) void dinv_kernel(float* __restrict__ deg, int N) {
    int i = blockIdx.x * blockDim.x + threadIdx.x;
    if (i < N) deg[i] = rsqrtf(deg[i] + 1.0f);  // self-loop guarantees deg>0
}

template <int K, int M>
__global__ __launch_bounds__(256) void matmul_kernel(const float* __restrict__ X,
                                                     const float* __restrict__ W,
                                                     float* __restrict__ H, int N) {
    __shared__ float Ws[K * M];
    for (int i = threadIdx.x; i < K * M; i += blockDim.x) Ws[i] = W[i];
    __syncthreads();
    int idx = blockIdx.x * blockDim.x + threadIdx.x;
    if (idx >= N * M) return;
    unsigned row = (unsigned)idx / M;
    unsigned c = (unsigned)idx % M;
    const float* xr = X + (size_t)row * K;
    float acc = 0.f;
#pragma unroll
    for (int k = 0; k < K; ++k) acc += xr[k] * Ws[k * M + c];
    H[idx] = acc;
}

// One 64-lane wave per edge; lanes [0,F) move one feature each.
template <int F>
__global__ __launch_bounds__(256) void agg_kernel(const int* __restrict__ row,
                                                  const int* __restrict__ col,
                                                  const float* __restrict__ dinv,
                                                  const float* __restrict__ H,
                                                  float* __restrict__ out, int E) {
    int wid = (blockIdx.x * blockDim.x + threadIdx.x) >> 6;
    int lane = threadIdx.x & 63;
    if (wid >= E) return;
    int r = row[wid];
    int c = col[wid];
    float norm = dinv[r] * dinv[c];
    if (lane < F) {
        float v = H[(size_t)r * F + lane] * norm;
        atomicAdd(&out[(size_t)c * F + lane], v);
    }
}

template <int F, bool RELU>
__global__ __launch_bounds__(256) void epilogue_kernel(float* __restrict__ out,
                                                       const float* __restrict__ H,
                                                       const float* __restrict__ dinv,
                                                       const float* __restrict__ b, int N) {
    int idx = blockIdx.x * blockDim.x + threadIdx.x;
    if (idx >= N * F) return;
    unsigned i = (unsigned)idx / F;
    unsigned f = (unsigned)idx % F;
    float d = dinv[i];
    float v = out[idx] + H[idx] * d * d + b[f];
    if (RELU) v = fmaxf(v, 0.f);
    out[idx] = v;
}

// One wave per decode edge: lane f multiplies z[a][f]*z[b][f], 64-wide butterfly sum.
__global__ __launch_bounds__(256) void decode_kernel(const int* __restrict__ pos,
                                                     const int* __restrict__ neg, int Ep, int En,
                                                     const float* __restrict__ z,
                                                     float* __restrict__ logits) {
    int wid = (blockIdx.x * blockDim.x + threadIdx.x) >> 6;
    int lane = threadIdx.x & 63;
    int Etot = Ep + En;
    if (wid >= Etot) return;
    int a, bn;
    if (wid < Ep) {
        a = pos[wid];
        bn = pos[Ep + wid];
    } else {
        int e = wid - Ep;
        a = neg[e];
        bn = neg[En + e];
    }
    float v = z[(size_t)a * 64 + lane] * z[(size_t)bn * 64 + lane];
#pragma unroll
    for (int off = 32; off > 0; off >>= 1) v += __shfl_down(v, off, 64);
    if (lane == 0) logits[wid] = v;
}

extern "C" void kernel_launch(void* const* d_in, const int* in_sizes, int n_in,
                              void* d_out, int out_size, void* d_ws, size_t ws_size,
                              hipStream_t stream) {
    const float* x = (const float*)d_in[0];
    const int* train = (const int*)d_in[1];
    const int* pos = (const int*)d_in[2];
    const int* neg = (const int*)d_in[3];
    const float* W1 = (const float*)d_in[4];
    const float* b1 = (const float*)d_in[5];
    const float* W2 = (const float*)d_in[6];
    const float* b2 = (const float*)d_in[7];
    float* logits = (float*)d_out;

    const int FIN = 50, H = 50, D = 64;
    const int N = in_sizes[0] / FIN;        // 50000
    const int E = in_sizes[1] / 2;          // 1600000
    const int Ep = in_sizes[2] / 2;         // 200000
    const int En = in_sizes[3] / 2;         // 200000

    const int* t_row = train;       // sources
    const int* t_col = train + E;   // targets

    float* wsf = (float*)d_ws;
    float* deg = wsf;                       // N  (becomes dinv)
    float* bufH = deg + N;                  // N*50 : h1 = x@W1
    float* bufO1 = bufH + (size_t)N * H;    // N*50 : agg -> relu'd hidden
    float* bufHZ = bufO1 + (size_t)N * H;   // N*64 : hz = hidden@W2
    float* bufO2 = bufHZ + (size_t)N * D;   // N*64 : agg -> z

    // zero accumulators (ws is poisoned every call)
    hipMemsetAsync(deg, 0, (size_t)N * sizeof(float), stream);
    hipMemsetAsync(bufO1, 0, (size_t)N * H * sizeof(float), stream);
    hipMemsetAsync(bufO2, 0, (size_t)N * D * sizeof(float), stream);

    // degree + inverse-sqrt
    deg_kernel<<<(E + 255) / 256, 256, 0, stream>>>(t_col, E, deg);
    dinv_kernel<<<(N + 255) / 256, 256, 0, stream>>>(deg, N);

    // layer 1
    matmul_kernel<50, 50><<<((size_t)N * H + 255) / 256, 256, 0, stream>>>(x, W1, bufH, N);
    {
        long long waves = (long long)E;
        int blocks = (int)((waves * 64 + 255) / 256);
        agg_kernel<50><<<blocks, 256, 0, stream>>>(t_row, t_col, deg, bufH, bufO1, E);
    }
    epilogue_kernel<50, true><<<((size_t)N * H + 255) / 256, 256, 0, stream>>>(bufO1, bufH, deg,
                                                                               b1, N);

    // layer 2
    matmul_kernel<50, 64><<<((size_t)N * D + 255) / 256, 256, 0, stream>>>(bufO1, W2, bufHZ, N);
    {
        long long waves = (long long)E;
        int blocks = (int)((waves * 64 + 255) / 256);
        agg_kernel<64><<<blocks, 256, 0, stream>>>(t_row, t_col, deg, bufHZ, bufO2, E);
    }
    epilogue_kernel<64, false><<<((size_t)N * D + 255) / 256, 256, 0, stream>>>(bufO2, bufHZ, deg,
                                                                                b2, N);

    // decode
    {
        long long waves = (long long)(Ep + En);
        int blocks = (int)((waves * 64 + 255) / 256);
        decode_kernel<<<blocks, 256, 0, stream>>>(pos, neg, Ep, En, bufO2, logits);
    }
}

// Round 2
// 742.131 us; speedup vs baseline: 1.3443x; 1.3443x over previous
//
#include <hip/hip_runtime.h>
#include <hip/hip_bf16.h>

// GCN link-prediction: 2x GCNConv + dot decoder. N=50000, F_in=50, H=50, D=64,
// E_train=1.6M, Ep=En=200k.
//
// R1 -> R2: replaced fp-atomic scatter aggregation (2x339us, 350MB atomic write
// traffic) with CSR build (int histogram + scan + cursor scatter, once per call,
// shared by both layers) + gather aggregation with register accumulation.
// Norm factored: out[c] = dinv[c]*(sum_r h[r]*dinv[r] + h[c]*dinv[c]) + b, so the
// matmul epilogue pre-scales hs = h*dinv and the gather kernel fuses self-loop,
// bias, relu. No zeroing of feature buffers needed anymore.

__global__ __launch_bounds__(256) void histo_kernel(const int* __restrict__ col, int E,
                                                    int* __restrict__ deg) {
    int i = blockIdx.x * blockDim.x + threadIdx.x;
    if (i < E) atomicAdd(&deg[col[i]], 1);
}

__global__ __launch_bounds__(256) void dinv_kernel(const int* __restrict__ deg,
                                                   float* __restrict__ dinv, int N) {
    int i = blockIdx.x * blockDim.x + threadIdx.x;
    if (i < N) dinv[i] = rsqrtf((float)deg[i] + 1.0f);  // +1 = self loop
}

// Single-block exclusive scan over N=50k degrees -> rowptr[N+1].
__global__ __launch_bounds__(1024) void scan_kernel(const int* __restrict__ deg,
                                                    int* __restrict__ rowptr, int N) {
    __shared__ int sums[1024];
    int t = threadIdx.x;
    const int CH = (N + 1023) / 1024;
    int begin = t * CH;
    int endi = begin < N ? min(begin + CH, N) : begin;
    int s = 0;
    for (int i = begin; i < endi; ++i) s += deg[i];
    sums[t] = s;
    __syncthreads();
    for (int off = 1; off < 1024; off <<= 1) {
        int v = (t >= off) ? sums[t - off] : 0;
        __syncthreads();
        sums[t] += v;
        __syncthreads();
    }
    int run = (t == 0) ? 0 : sums[t - 1];
    for (int i = begin; i < endi; ++i) {
        rowptr[i] = run;
        run += deg[i];
    }
    if (t == 1023) rowptr[N] = run;
}

__global__ __launch_bounds__(256) void scatter_kernel(const int* __restrict__ row,
                                                      const int* __restrict__ col,
                                                      const int* __restrict__ rowptr,
                                                      int* __restrict__ cnt,
                                                      int* __restrict__ srcIdx, int E) {
    int i = blockIdx.x * blockDim.x + threadIdx.x;
    if (i < E) {
        int c = col[i];
        int p = rowptr[c] + atomicAdd(&cnt[c], 1);
        srcIdx[p] = row[i];
    }
}

// H_out[i,:] = (X[i,:] @ W) * dinv[i]   (pre-scaled messages)
template <int K, int M>
__global__ __launch_bounds__(256) void matmul_scale_kernel(const float* __restrict__ X,
                                                           const float* __restrict__ W,
                                                           const float* __restrict__ dinv,
                                                           float* __restrict__ Hs, int N) {
    __shared__ float Ws[K * M];
    for (int i = threadIdx.x; i < K * M; i += blockDim.x) Ws[i] = W[i];
    __syncthreads();
    int idx = blockIdx.x * blockDim.x + threadIdx.x;
    if (idx >= N * M) return;
    unsigned row = (unsigned)idx / M;
    unsigned c = (unsigned)idx % M;
    const float* xr = X + (size_t)row * K;
    float acc = 0.f;
#pragma unroll
    for (int k = 0; k < K; ++k) acc += xr[k] * Ws[k * M + c];
    Hs[idx] = acc * dinv[row];
}

// One wave per node, lane = feature. acc = sum over incoming edges of hs[src],
// out = dinv[node]*(acc + hs[node]) + b, optional relu.
template <int F, bool RELU>
__global__ __launch_bounds__(256) void agg_gather_kernel(const int* __restrict__ rowptr,
                                                         const int* __restrict__ srcIdx,
                                                         const float* __restrict__ hs,
                                                         const float* __restrict__ dinv,
                                                         const float* __restrict__ b,
                                                         float* __restrict__ out, int N) {
    int wid = (blockIdx.x * blockDim.x + threadIdx.x) >> 6;
    int lane = threadIdx.x & 63;
    if (wid >= N) return;
    int start = rowptr[wid];
    int end = rowptr[wid + 1];
    if (lane < F) {
        float acc = 0.f;
        for (int j = start; j < end; ++j) {
            int r = srcIdx[j];
            acc += hs[(size_t)r * F + lane];
        }
        acc += hs[(size_t)wid * F + lane];  // self loop (hs already has dinv[src])
        float v = dinv[wid] * acc + b[lane];
        if (RELU) v = fmaxf(v, 0.f);
        out[(size_t)wid * F + lane] = v;
    }
}

// One wave per decode edge: lane f multiplies z[a][f]*z[b][f], butterfly sum.
__global__ __launch_bounds__(256) void decode_kernel(const int* __restrict__ pos,
                                                     const int* __restrict__ neg, int Ep, int En,
                                                     const float* __restrict__ z,
                                                     float* __restrict__ logits) {
    int wid = (blockIdx.x * blockDim.x + threadIdx.x) >> 6;
    int lane = threadIdx.x & 63;
    int Etot = Ep + En;
    if (wid >= Etot) return;
    int a, bn;
    if (wid < Ep) {
        a = pos[wid];
        bn = pos[Ep + wid];
    } else {
        int e = wid - Ep;
        a = neg[e];
        bn = neg[En + e];
    }
    float v = z[(size_t)a * 64 + lane] * z[(size_t)bn * 64 + lane];
#pragma unroll
    for (int off = 32; off > 0; off >>= 1) v += __shfl_down(v, off, 64);
    if (lane == 0) logits[wid] = v;
}

extern "C" void kernel_launch(void* const* d_in, const int* in_sizes, int n_in,
                              void* d_out, int out_size, void* d_ws, size_t ws_size,
                              hipStream_t stream) {
    const float* x = (const float*)d_in[0];
    const int* train = (const int*)d_in[1];
    const int* pos = (const int*)d_in[2];
    const int* neg = (const int*)d_in[3];
    const float* W1 = (const float*)d_in[4];
    const float* b1 = (const float*)d_in[5];
    const float* W2 = (const float*)d_in[6];
    const float* b2 = (const float*)d_in[7];
    float* logits = (float*)d_out;

    const int FIN = 50, H = 50, D = 64;
    const int N = in_sizes[0] / FIN;  // 50000
    const int E = in_sizes[1] / 2;    // 1600000
    const int Ep = in_sizes[2] / 2;   // 200000
    const int En = in_sizes[3] / 2;   // 200000

    const int* t_row = train;      // sources
    const int* t_col = train + E;  // targets

    // ws layout (all 4B elems): dinv[N] | buf0[N*64] | buf1[N*64] |
    //                           deg[N] | cnt[N] | rowptr[N+1] | srcIdx[E]
    float* dinv = (float*)d_ws;
    float* buf0 = dinv + N;
    float* buf1 = buf0 + (size_t)N * 64;
    int* deg = (int*)(buf1 + (size_t)N * 64);
    int* cnt = deg + N;
    int* rowptr = cnt + N;
    int* srcIdx = rowptr + (N + 1);

    // zero the int accumulators (ws is poisoned every call)
    hipMemsetAsync(deg, 0, (size_t)2 * N * sizeof(int), stream);  // deg + cnt

    // CSR build (shared by both layers)
    histo_kernel<<<(E + 255) / 256, 256, 0, stream>>>(t_col, E, deg);
    dinv_kernel<<<(N + 255) / 256, 256, 0, stream>>>(deg, dinv, N);
    scan_kernel<<<1, 1024, 0, stream>>>(deg, rowptr, N);
    scatter_kernel<<<(E + 255) / 256, 256, 0, stream>>>(t_row, t_col, rowptr, cnt, srcIdx, E);

    // layer 1: hs1 = (x@W1)*dinv -> buf0 ; agg -> relu'd hidden -> buf1
    matmul_scale_kernel<50, 50><<<((size_t)N * H + 255) / 256, 256, 0, stream>>>(x, W1, dinv,
                                                                                 buf0, N);
    agg_gather_kernel<50, true><<<(N * 64 + 255) / 256, 256, 0, stream>>>(rowptr, srcIdx, buf0,
                                                                          dinv, b1, buf1, N);

    // layer 2: hs2 = (hidden@W2)*dinv -> buf0 ; agg -> z -> buf1
    matmul_scale_kernel<50, 64><<<((size_t)N * D + 255) / 256, 256, 0, stream>>>(buf1, W2, dinv,
                                                                                 buf0, N);
    agg_gather_kernel<64, false><<<(N * 64 + 255) / 256, 256, 0, stream>>>(rowptr, srcIdx, buf0,
                                                                           dinv, b2, buf1, N);

    // decode from z = buf1
    {
        long long waves = (long long)(Ep + En);
        int blocks = (int)((waves * 64 + 255) / 256);
        decode_kernel<<<blocks, 256, 0, stream>>>(pos, neg, Ep, En, buf1, logits);
    }
}

// Round 3
// 563.042 us; speedup vs baseline: 1.7718x; 1.3181x over previous
//
#include <hip/hip_runtime.h>
#include <hip/hip_bf16.h>

// GCN link-prediction: 2x GCNConv + dot decoder. N=50000, F_in=50, H=50, D=64,
// E_train=1.6M, Ep=En=200k.
//
// R2 -> R3: aggregation/decode restructured for memory-level parallelism.
// All feature buffers padded to N x 64 floats. Gather kernel: 16 lanes per node
// (float4 per lane), 4 nodes per wave, 4x edge unroll -> ~16 outstanding loads
// per wave (was ~1: serial srcIdx->hs chain, 145us latency-bound). Decode: 16
// lanes per edge, 4 edges per wave, shfl_xor reduce within 16-lane groups.

__global__ __launch_bounds__(256) void histo_kernel(const int* __restrict__ col, int E,
                                                    int* __restrict__ deg) {
    int i = blockIdx.x * blockDim.x + threadIdx.x;
    if (i < E) atomicAdd(&deg[col[i]], 1);
}

__global__ __launch_bounds__(256) void dinv_kernel(const int* __restrict__ deg,
                                                   float* __restrict__ dinv, int N) {
    int i = blockIdx.x * blockDim.x + threadIdx.x;
    if (i < N) dinv[i] = rsqrtf((float)deg[i] + 1.0f);  // +1 = self loop
}

// Single-block exclusive scan over N=50k degrees -> rowptr[N+1].
__global__ __launch_bounds__(1024) void scan_kernel(const int* __restrict__ deg,
                                                    int* __restrict__ rowptr, int N) {
    __shared__ int sums[1024];
    int t = threadIdx.x;
    const int CH = (N + 1023) / 1024;
    int begin = t * CH;
    int endi = begin < N ? min(begin + CH, N) : begin;
    int s = 0;
    for (int i = begin; i < endi; ++i) s += deg[i];
    sums[t] = s;
    __syncthreads();
    for (int off = 1; off < 1024; off <<= 1) {
        int v = (t >= off) ? sums[t - off] : 0;
        __syncthreads();
        sums[t] += v;
        __syncthreads();
    }
    int run = (t == 0) ? 0 : sums[t - 1];
    for (int i = begin; i < endi; ++i) {
        rowptr[i] = run;
        run += deg[i];
    }
    if (t == 1023) rowptr[N] = run;
}

__global__ __launch_bounds__(256) void scatter_kernel(const int* __restrict__ row,
                                                      const int* __restrict__ col,
                                                      const int* __restrict__ rowptr,
                                                      int* __restrict__ cnt,
                                                      int* __restrict__ srcIdx, int E) {
    int i = blockIdx.x * blockDim.x + threadIdx.x;
    if (i < E) {
        int c = col[i];
        int p = rowptr[c] + atomicAdd(&cnt[c], 1);
        srcIdx[p] = row[i];
    }
}

// Hs[i, 0:64] = pad64( (X[i,:] @ W) * dinv[i] ); pad cols (c>=MV) = 0.
// INS = input row stride, K = inner dim, MV = valid output cols.
template <int K, int INS, int MV>
__global__ __launch_bounds__(256) void matmul_scale_kernel(const float* __restrict__ X,
                                                           const float* __restrict__ W,
                                                           const float* __restrict__ dinv,
                                                           float* __restrict__ Hs, int N) {
    __shared__ float Ws[K * MV];
    for (int i = threadIdx.x; i < K * MV; i += blockDim.x) Ws[i] = W[i];
    __syncthreads();
    int idx = blockIdx.x * blockDim.x + threadIdx.x;
    int row = idx >> 6;
    int c = idx & 63;
    if (row >= N) return;
    float out = 0.f;
    if (c < MV) {
        const float* xr = X + (size_t)row * INS;
        float acc = 0.f;
#pragma unroll
        for (int k = 0; k < K; ++k) acc += xr[k] * Ws[k * MV + c];
        out = acc * dinv[row];
    }
    Hs[(size_t)row * 64 + c] = out;
}

// 16 lanes per node (float4 each), 4 nodes per wave, 4x edge unroll.
// out[n,:] = dinv[n]*(sum_src hs[src,:] + hs[n,:]) + b  (+relu). Rows are 64f.
template <int BC, bool RELU>
__global__ __launch_bounds__(256) void agg_gather_kernel(const int* __restrict__ rowptr,
                                                         const int* __restrict__ srcIdx,
                                                         const float4* __restrict__ hs,
                                                         const float* __restrict__ dinv,
                                                         const float* __restrict__ b,
                                                         float4* __restrict__ out, int N) {
    int tid = blockIdx.x * blockDim.x + threadIdx.x;
    int node = tid >> 4;
    int q = tid & 15;  // float4 slot within the 64-float row
    if (node >= N) return;
    int start = rowptr[node];
    int end = rowptr[node + 1];
    float4 acc = make_float4(0.f, 0.f, 0.f, 0.f);
    int j = start;
    for (; j + 4 <= end; j += 4) {
        int r0 = srcIdx[j + 0];
        int r1 = srcIdx[j + 1];
        int r2 = srcIdx[j + 2];
        int r3 = srcIdx[j + 3];
        float4 a0 = hs[(size_t)r0 * 16 + q];
        float4 a1 = hs[(size_t)r1 * 16 + q];
        float4 a2 = hs[(size_t)r2 * 16 + q];
        float4 a3 = hs[(size_t)r3 * 16 + q];
        acc.x += a0.x + a1.x + a2.x + a3.x;
        acc.y += a0.y + a1.y + a2.y + a3.y;
        acc.z += a0.z + a1.z + a2.z + a3.z;
        acc.w += a0.w + a1.w + a2.w + a3.w;
    }
    for (; j < end; ++j) {
        int r = srcIdx[j];
        float4 a = hs[(size_t)r * 16 + q];
        acc.x += a.x;
        acc.y += a.y;
        acc.z += a.z;
        acc.w += a.w;
    }
    float4 s = hs[(size_t)node * 16 + q];  // self loop (hs already *dinv[src])
    acc.x += s.x;
    acc.y += s.y;
    acc.z += s.z;
    acc.w += s.w;
    float d = dinv[node];
    int f = q * 4;
    float4 v;
    v.x = d * acc.x + (f + 0 < BC ? b[f + 0] : 0.f);
    v.y = d * acc.y + (f + 1 < BC ? b[f + 1] : 0.f);
    v.z = d * acc.z + (f + 2 < BC ? b[f + 2] : 0.f);
    v.w = d * acc.w + (f + 3 < BC ? b[f + 3] : 0.f);
    if (RELU) {
        v.x = fmaxf(v.x, 0.f);
        v.y = fmaxf(v.y, 0.f);
        v.z = fmaxf(v.z, 0.f);
        v.w = fmaxf(v.w, 0.f);
    }
    out[(size_t)node * 16 + q] = v;
}

// 16 lanes per edge, 4 edges per wave; dot over 64 floats via float4 + shfl_xor.
__global__ __launch_bounds__(256) void decode_kernel(const int* __restrict__ pos,
                                                     const int* __restrict__ neg, int Ep, int En,
                                                     const float4* __restrict__ z,
                                                     float* __restrict__ logits) {
    int tid = blockIdx.x * blockDim.x + threadIdx.x;
    int e = tid >> 4;
    int q = tid & 15;
    int Etot = Ep + En;
    if (e >= Etot) return;
    int a, bn;
    if (e < Ep) {
        a = pos[e];
        bn = pos[Ep + e];
    } else {
        int t = e - Ep;
        a = neg[t];
        bn = neg[En + t];
    }
    float4 za = z[(size_t)a * 16 + q];
    float4 zb = z[(size_t)bn * 16 + q];
    float v = za.x * zb.x + za.y * zb.y + za.z * zb.z + za.w * zb.w;
    v += __shfl_xor(v, 1, 64);
    v += __shfl_xor(v, 2, 64);
    v += __shfl_xor(v, 4, 64);
    v += __shfl_xor(v, 8, 64);
    if (q == 0) logits[e] = v;
}

extern "C" void kernel_launch(void* const* d_in, const int* in_sizes, int n_in,
                              void* d_out, int out_size, void* d_ws, size_t ws_size,
                              hipStream_t stream) {
    const float* x = (const float*)d_in[0];
    const int* train = (const int*)d_in[1];
    const int* pos = (const int*)d_in[2];
    const int* neg = (const int*)d_in[3];
    const float* W1 = (const float*)d_in[4];
    const float* b1 = (const float*)d_in[5];
    const float* W2 = (const float*)d_in[6];
    const float* b2 = (const float*)d_in[7];
    float* logits = (float*)d_out;

    const int FIN = 50, H = 50, D = 64;
    const int N = in_sizes[0] / FIN;  // 50000
    const int E = in_sizes[1] / 2;    // 1600000
    const int Ep = in_sizes[2] / 2;   // 200000
    const int En = in_sizes[3] / 2;   // 200000

    const int* t_row = train;      // sources
    const int* t_col = train + E;  // targets

    // ws layout (4B elems, buffers 16B aligned): dinv[N] | buf0[N*64] | buf1[N*64]
    //   | deg[N] | cnt[N] | rowptr[N+1] | srcIdx[E]
    float* dinv = (float*)d_ws;
    float* buf0 = dinv + N;
    float* buf1 = buf0 + (size_t)N * 64;
    int* deg = (int*)(buf1 + (size_t)N * 64);
    int* cnt = deg + N;
    int* rowptr = cnt + N;
    int* srcIdx = rowptr + (N + 1);

    // zero the int accumulators (ws is poisoned every call)
    hipMemsetAsync(deg, 0, (size_t)2 * N * sizeof(int), stream);  // deg + cnt

    // CSR build (shared by both layers)
    histo_kernel<<<(E + 255) / 256, 256, 0, stream>>>(t_col, E, deg);
    dinv_kernel<<<(N + 255) / 256, 256, 0, stream>>>(deg, dinv, N);
    scan_kernel<<<1, 1024, 0, stream>>>(deg, rowptr, N);
    scatter_kernel<<<(E + 255) / 256, 256, 0, stream>>>(t_row, t_col, rowptr, cnt, srcIdx, E);

    const int NT = N * 64;  // padded elements per feature buffer

    // layer 1: hs1 = pad64((x@W1)*dinv) -> buf0 ; agg (+b1, relu) -> buf1
    matmul_scale_kernel<50, 50, 50><<<(NT + 255) / 256, 256, 0, stream>>>(x, W1, dinv, buf0, N);
    agg_gather_kernel<50, true><<<(N * 16 + 255) / 256, 256, 0, stream>>>(
        rowptr, srcIdx, (const float4*)buf0, dinv, b1, (float4*)buf1, N);

    // layer 2: hs2 = (hidden@W2)*dinv -> buf0 ; agg (+b2) -> z -> buf1
    matmul_scale_kernel<50, 64, 64><<<(NT + 255) / 256, 256, 0, stream>>>(buf1, W2, dinv, buf0, N);
    agg_gather_kernel<64, false><<<(N * 16 + 255) / 256, 256, 0, stream>>>(
        rowptr, srcIdx, (const float4*)buf0, dinv, b2, (float4*)buf1, N);

    // decode from z = buf1
    decode_kernel<<<((Ep + En) * 16 + 255) / 256, 256, 0, stream>>>(pos, neg, Ep, En,
                                                                    (const float4*)buf1, logits);
}